// Round 1
// 356.034 us; speedup vs baseline: 1.0562x; 1.0562x over previous
//
#include <hip/hip_runtime.h>
#include <hip/hip_bf16.h>

typedef __hip_bfloat16 bf16;
typedef __attribute__((ext_vector_type(8))) short bf16x8;   // 8 bf16 = 4 VGPRs (MFMA A/B frag)
typedef __attribute__((ext_vector_type(4))) float f32x4;    // MFMA C/D frag

#define ASYNC_CP16(gsrc, ldst)                                                              \
  __builtin_amdgcn_global_load_lds(                                                         \
      (const __attribute__((address_space(1))) unsigned int*)(gsrc),                        \
      (__attribute__((address_space(3))) unsigned int*)(ldst), 16, 0, 0)

#define BB 32
#define NN 1024
#define FF 512
#define HH 2048
#define M_ROWS (BB * NN)  // 32768

// ---------------------------------------------------------------- weight casts (fused)
__global__ __launch_bounds__(256) void cvt_pair(const float* __restrict__ a, bf16* __restrict__ da,
                                                const float* __restrict__ b, bf16* __restrict__ db,
                                                int n) {
  int i = blockIdx.x * 256 + threadIdx.x;
  if (i < n) {
    da[i] = __float2bfloat16(a[i]);
    db[i] = __float2bfloat16(b[i]);
  }
}

// ---------------------------------------------------------------- DPP xor-exchange (VALU pipe)
template <int CTRL>
__device__ __forceinline__ unsigned long long dpp_xor64(unsigned long long k) {
  int lo = (int)(unsigned)k;
  int hi = (int)(unsigned)(k >> 32);
  int plo = __builtin_amdgcn_update_dpp(lo, lo, CTRL, 0xF, 0xF, false);
  int phi = __builtin_amdgcn_update_dpp(hi, hi, CTRL, 0xF, 0xF, false);
  return (((unsigned long long)(unsigned)phi) << 32) | (unsigned)plo;
}

// ---------------------------------------------------------------- stable argsort per row
__global__ __launch_bounds__(256) void sort_rows_wave(const float* __restrict__ x,
                                                      unsigned* __restrict__ xs_pack,
                                                      unsigned* __restrict__ srt_pack) {
  __shared__ __align__(16) unsigned short scatx[4 * FF];  // 4 waves/block, 512 u16 per row
  const int t = threadIdx.x;
  const int lane = t & 63;
  const int w = t >> 6;
  const size_t row = (size_t)blockIdx.x * 4 + w;
  const float* xr = x + row * FF;

  float4 v0 = *(const float4*)(xr + lane * 8);
  float4 v1 = *(const float4*)(xr + lane * 8 + 4);
  float vals[8] = {v0.x, v0.y, v0.z, v0.w, v1.x, v1.y, v1.z, v1.w};

  unsigned long long key[8];
#pragma unroll
  for (int r = 0; r < 8; r++) {
    unsigned u = __float_as_uint(vals[r]);
    unsigned s = u ^ ((unsigned)((int)u >> 31) | 0x80000000u);  // monotone fp32->u32
    key[r] = ((unsigned long long)s << 32) | (unsigned)(lane * 8 + r);
  }

#pragma unroll
  for (int k = 2; k <= 512; k <<= 1) {
#pragma unroll
    for (int j = k >> 1; j > 0; j >>= 1) {
      if (j >= 8) {
        const int d = j >> 3;  // lane distance
#pragma unroll
        for (int r = 0; r < 8; r++) {
          unsigned long long o;
          if (d == 1)       o = dpp_xor64<0xB1>(key[r]);
          else if (d == 2)  o = dpp_xor64<0x4E>(key[r]);
          else if (d == 8)  o = dpp_xor64<0x128>(key[r]);
          else              o = __shfl_xor(key[r], d, 64);
          bool asc = (((lane * 8 + r) & k) == 0);
          bool lower = ((lane & d) == 0);
          bool keepmin = (asc == lower);
          bool minemin = key[r] < o;
          key[r] = (minemin == keepmin) ? key[r] : o;
        }
      } else {
#pragma unroll
        for (int r = 0; r < 8; r++) {
          if ((r & j) == 0) {
            const int a = r, b = r | j;
            bool asc = (((lane * 8 + a) & k) == 0);
            unsigned long long ka = key[a], kb = key[b];
            bool sw = ((ka > kb) == asc);
            key[a] = sw ? kb : ka;
            key[b] = sw ? ka : kb;
          }
        }
      }
    }
  }

  const int base = w * FF;
  unsigned j8[8];
#pragma unroll
  for (int r = 0; r < 8; r++) {
    j8[r] = (unsigned)key[r] & 0xFFFFu;
    __hip_bfloat16 hb = __float2bfloat16(vals[r]);
    scatx[base + j8[r]] = *(unsigned short*)&hb;
  }

  uint4 so;
  so.x = j8[0] | (j8[1] << 16);
  so.y = j8[2] | (j8[3] << 16);
  so.z = j8[4] | (j8[5] << 16);
  so.w = j8[6] | (j8[7] << 16);
  *(uint4*)(srt_pack + row * 256 + lane * 4) = so;

  __syncthreads();
  uint4 xo = *(const uint4*)&scatx[base + lane * 8];
  *(uint4*)(xs_pack + row * 256 + lane * 4) = xo;
}

// ---------------------------------------------------------------- 8-phase 256x256 GEMM (T2+T3+T4+T5)
// 512 threads = 8 waves (2 waveM x 4 waveN); per-wave output 128x64; BK=64 split as 2 k-halves of 32.
// LDS 128 KiB: A[2buf][2kh][256][32] at S[0..32768), B same at S[32768..65536), bf16.
// Swizzle (T2): 16B slot-in-row c_phys = c_log ^ ((row>>1)&3). global_load_lds writes linearly,
// so the SOURCE is pre-swizzled (rule #21) and ds_read applies the same XOR.
// Schedule (T3/T4): per K-tile 4 phases (mh,ks); phase = {ds_read frags; issue 1 half-stage (2 loads);
// s_barrier; lgkmcnt(0); setprio(1); 16 MFMA; setprio(0); [vmcnt(4) at P2/P4]; s_barrier}.
// Staging order A0,B0,A1,B1 of tile t+1 during tile t; vmcnt(4) never drains the pipe:
//   end-P2: completes (t,A1),(t,B1) needed by P3/P4; end-P4: completes (t+1,A0),(t+1,B0) for next P1.
// NO __syncthreads anywhere (it would drain vmcnt(0) and kill the pipeline).
template <int RELU, int ADDX, int K, int N>
__global__ __launch_bounds__(512, 2) void gemm8p(const bf16* __restrict__ A,
                                                 const bf16* __restrict__ Bw,
                                                 const float* __restrict__ bias,
                                                 const bf16* __restrict__ xs_add,
                                                 bf16* __restrict__ C) {
  __shared__ __align__(16) bf16 S[65536];  // 128 KiB
  const int t = threadIdx.x;
  const int lane = t & 63, wave = t >> 6;
  const int waveM = wave >> 2, waveN = wave & 3;
  const size_t mBase = (size_t)blockIdx.x * 256;
  const size_t nBase = (size_t)blockIdx.y * 256;

  // staging: thread covers 16B slot s = t (+512 for second load); row = s>>2, pre-swizzled col
  const int srow = t >> 2;                        // 0..127 (second load: +128)
  const int sclog = (t & 3) ^ ((t >> 3) & 3);     // inverse-swizzled source col slot
  const bf16* Asrc0 = A + (mBase + srow) * (size_t)K + sclog * 8;
  const bf16* Bsrc0 = Bw + (nBase + srow) * (size_t)K + sclog * 8;
  const int sdA = wave * 512;                     // LDS dest (elements), + region base
  const int sdB = 32768 + wave * 512;

  // fragment reads: row = (tile-row) + fr, swizzled 16B slot = (lane>>4) ^ ((fr>>1)&3)
  const int fr = lane & 15;
  const int swz8 = ((lane >> 4) ^ ((lane >> 1) & 3)) * 8;
  const int aRd = (waveM * 128 + fr) * 32 + swz8;           // + region + mh*2048 + i*512
  const int bRd = 32768 + (waveN * 64 + fr) * 32 + swz8;    // + region(buf,ks) + nt*512

#define STAGE_A(tt, ks)                                           \
  do {                                                            \
    const int rb_ = (((tt) & 1) * 2 + (ks)) * 8192 + sdA;         \
    const bf16* g_ = Asrc0 + (size_t)(tt) * 64 + (ks) * 32;       \
    ASYNC_CP16(g_, &S[rb_]);                                      \
    ASYNC_CP16(g_ + (size_t)128 * K, &S[rb_ + 4096]);             \
  } while (0)
#define STAGE_B(tt, ks)                                           \
  do {                                                            \
    const int rb_ = (((tt) & 1) * 2 + (ks)) * 8192 + sdB;         \
    const bf16* g_ = Bsrc0 + (size_t)(tt) * 64 + (ks) * 32;       \
    ASYNC_CP16(g_, &S[rb_]);                                      \
    ASYNC_CP16(g_ + (size_t)128 * K, &S[rb_ + 4096]);             \
  } while (0)

  f32x4 acc[8][4];
  f32x4 zero = {0.f, 0.f, 0.f, 0.f};
#pragma unroll
  for (int i = 0; i < 8; i++)
#pragma unroll
    for (int j = 0; j < 4; j++) acc[i][j] = zero;

  // prologue: stage tile 0 fully; k0 halves guaranteed, k1 halves stay in flight
  STAGE_A(0, 0);
  STAGE_B(0, 0);
  STAGE_A(0, 1);
  STAGE_B(0, 1);
  asm volatile("s_waitcnt vmcnt(4)" ::: "memory");
  __builtin_amdgcn_s_barrier();

  const int NT = K / 64;
  for (int kt = 0; kt < NT; ++kt) {
    const int buf = kt & 1;
    const bool pf = (kt + 1 < NT);
    bf16x8 af[4], bq[4];

    // ---- P1: (mh=0, ks=0)
    {
      const int rg = buf * 16384;
#pragma unroll
      for (int i = 0; i < 4; i++) af[i] = *(const bf16x8*)&S[rg + aRd + i * 512];
#pragma unroll
      for (int n = 0; n < 4; n++) bq[n] = *(const bf16x8*)&S[rg + bRd + n * 512];
      if (pf) STAGE_A(kt + 1, 0);
      __builtin_amdgcn_s_barrier();
      asm volatile("s_waitcnt lgkmcnt(0)" ::: "memory");
      __builtin_amdgcn_sched_barrier(0);
      __builtin_amdgcn_s_setprio(1);
#pragma unroll
      for (int i = 0; i < 4; i++)
#pragma unroll
        for (int n = 0; n < 4; n++)
          acc[i][n] = __builtin_amdgcn_mfma_f32_16x16x32_bf16(af[i], bq[n], acc[i][n], 0, 0, 0);
      __builtin_amdgcn_s_setprio(0);
      __builtin_amdgcn_s_barrier();
    }
    // ---- P2: (mh=1, ks=0) — reuse bq
    {
      const int rg = buf * 16384;
#pragma unroll
      for (int i = 0; i < 4; i++) af[i] = *(const bf16x8*)&S[rg + aRd + 2048 + i * 512];
      if (pf) STAGE_B(kt + 1, 0);
      __builtin_amdgcn_s_barrier();
      asm volatile("s_waitcnt lgkmcnt(0)" ::: "memory");
      __builtin_amdgcn_sched_barrier(0);
      __builtin_amdgcn_s_setprio(1);
#pragma unroll
      for (int i = 0; i < 4; i++)
#pragma unroll
        for (int n = 0; n < 4; n++)
          acc[4 + i][n] = __builtin_amdgcn_mfma_f32_16x16x32_bf16(af[i], bq[n], acc[4 + i][n], 0, 0, 0);
      __builtin_amdgcn_s_setprio(0);
      if (pf) asm volatile("s_waitcnt vmcnt(4)" ::: "memory");
      else    asm volatile("s_waitcnt vmcnt(0)" ::: "memory");
      __builtin_amdgcn_s_barrier();
    }
    // ---- P3: (mh=0, ks=1)
    {
      const int rg = buf * 16384 + 8192;
#pragma unroll
      for (int i = 0; i < 4; i++) af[i] = *(const bf16x8*)&S[rg + aRd + i * 512];
#pragma unroll
      for (int n = 0; n < 4; n++) bq[n] = *(const bf16x8*)&S[rg + bRd + n * 512];
      if (pf) STAGE_A(kt + 1, 1);
      __builtin_amdgcn_s_barrier();
      asm volatile("s_waitcnt lgkmcnt(0)" ::: "memory");
      __builtin_amdgcn_sched_barrier(0);
      __builtin_amdgcn_s_setprio(1);
#pragma unroll
      for (int i = 0; i < 4; i++)
#pragma unroll
        for (int n = 0; n < 4; n++)
          acc[i][n] = __builtin_amdgcn_mfma_f32_16x16x32_bf16(af[i], bq[n], acc[i][n], 0, 0, 0);
      __builtin_amdgcn_s_setprio(0);
      __builtin_amdgcn_s_barrier();
    }
    // ---- P4: (mh=1, ks=1)
    {
      const int rg = buf * 16384 + 8192;
#pragma unroll
      for (int i = 0; i < 4; i++) af[i] = *(const bf16x8*)&S[rg + aRd + 2048 + i * 512];
      if (pf) STAGE_B(kt + 1, 1);
      __builtin_amdgcn_s_barrier();
      asm volatile("s_waitcnt lgkmcnt(0)" ::: "memory");
      __builtin_amdgcn_sched_barrier(0);
      __builtin_amdgcn_s_setprio(1);
#pragma unroll
      for (int i = 0; i < 4; i++)
#pragma unroll
        for (int n = 0; n < 4; n++)
          acc[4 + i][n] = __builtin_amdgcn_mfma_f32_16x16x32_bf16(af[i], bq[n], acc[4 + i][n], 0, 0, 0);
      __builtin_amdgcn_s_setprio(0);
      if (pf) asm volatile("s_waitcnt vmcnt(4)" ::: "memory");
      __builtin_amdgcn_s_barrier();
    }
  }
#undef STAGE_A
#undef STAGE_B

  // epilogue: C/D layout col=lane&15, row=(lane>>4)*4+reg (harness-verified mapping)
  const int cn = lane & 15;
  const int cm = (lane >> 4) * 4;
  float b4[4];
#pragma unroll
  for (int n = 0; n < 4; n++) b4[n] = bias[nBase + waveN * 64 + n * 16 + cn];
#pragma unroll
  for (int mt = 0; mt < 8; mt++) {
#pragma unroll
    for (int n = 0; n < 4; n++) {
      size_t gn = nBase + waveN * 64 + n * 16 + cn;
#pragma unroll
      for (int r = 0; r < 4; r++) {
        size_t gm = mBase + waveM * 128 + mt * 16 + cm + r;
        float v = acc[mt][n][r] + b4[n];
        if (RELU) v = fmaxf(v, 0.f);
        if (ADDX) v += __bfloat162float(xs_add[gm * (size_t)N + gn]);
        C[gm * (size_t)N + gn] = __float2bfloat16(v);
      }
    }
  }
}

// ---------------------------------------------------------------- final permute (pure gather)
__global__ __launch_bounds__(256) void permute_gather(const bf16* __restrict__ zp,
                                                      const unsigned* __restrict__ srt_pack,
                                                      float* __restrict__ out) {
  __shared__ __align__(16) unsigned short zr[4][FF];
  const int t = threadIdx.x;
  const int lane = t & 63;
  const int w = t >> 6;
  const size_t row = (size_t)blockIdx.x * 4 + w;

  *(uint4*)&zr[w][lane * 8] = *(const uint4*)(zp + row * FF + lane * 8);
  uint4 sv = *(const uint4*)(srt_pack + row * 256 + lane * 4);
  __syncthreads();

  unsigned idx[8] = {sv.x & 0xFFFFu, sv.x >> 16, sv.y & 0xFFFFu, sv.y >> 16,
                     sv.z & 0xFFFFu, sv.z >> 16, sv.w & 0xFFFFu, sv.w >> 16};
  float4 o0, o1;
#pragma unroll
  for (int r = 0; r < 8; r++) {
    float zf = __uint_as_float(((unsigned)zr[w][idx[r]]) << 16);
    ((r < 4) ? (&o0.x) : (&o1.x))[r & 3] = zf;
  }
  *(float4*)(out + row * FF + lane * 8) = o0;
  *(float4*)(out + row * FF + lane * 8 + 4) = o1;
}

// ---------------------------------------------------------------- launch
extern "C" void kernel_launch(void* const* d_in, const int* in_sizes, int n_in,
                              void* d_out, int out_size, void* d_ws, size_t ws_size,
                              hipStream_t stream) {
  const float* x  = (const float*)d_in[0];
  const float* W1 = (const float*)d_in[1];
  const float* b1 = (const float*)d_in[2];
  const float* W2 = (const float*)d_in[3];
  const float* b2 = (const float*)d_in[4];
  float* out = (float*)d_out;

  char* ws = (char*)d_ws;
  // z aliases xs ([M][512] bf16, identical layout): gemm2 reads xs(gm,gn) then writes
  // z(gm,gn) from the SAME thread, tiles disjoint across blocks -> safe.
  unsigned* xs  = (unsigned*)(ws);                           // 32 MiB bf16 xs
  bf16*     xsb = (bf16*)(ws);
  bf16*     z   = (bf16*)(ws);                               // aliases xs
  unsigned* srt = (unsigned*)(ws + 33554432);                // 32 MiB u16 srt
  bf16* h   = (bf16*)(ws + 67108864);                        // 128 MiB
  bf16* W1b = (bf16*)(ws + 201326592);                       // 2 MiB
  bf16* W2b = (bf16*)(ws + 203423744);                       // 2 MiB

  cvt_pair<<<(HH * FF + 255) / 256, 256, 0, stream>>>(W1, W1b, W2, W2b, HH * FF);
  sort_rows_wave<<<M_ROWS / 4, 256, 0, stream>>>(x, xs, srt);
  // h = relu(xs @ W1^T + b1): M=32768, K=512, N=2048
  gemm8p<1, 0, FF, HH><<<dim3(M_ROWS / 256, HH / 256), 512, 0, stream>>>(xsb, W1b, b1, nullptr, h);
  // z = h @ W2^T + b2 + xs: M=32768, K=2048, N=512  (skip fused, sorted domain)
  gemm8p<0, 1, HH, FF><<<dim3(M_ROWS / 256, FF / 256), 512, 0, stream>>>(h, W2b, b2, xsb, z);
  permute_gather<<<M_ROWS / 4, 256, 0, stream>>>(z, srt, out);
}

// Round 3
// 348.608 us; speedup vs baseline: 1.0787x; 1.0213x over previous
//
#include <hip/hip_runtime.h>
#include <hip/hip_bf16.h>

typedef __hip_bfloat16 bf16;
typedef __attribute__((ext_vector_type(8))) short bf16x8;   // 8 bf16 = 4 VGPRs (MFMA A/B frag)
typedef __attribute__((ext_vector_type(4))) float f32x4;    // MFMA C/D frag

#define ASYNC_CP16(gsrc, ldst)                                                              \
  __builtin_amdgcn_global_load_lds(                                                         \
      (const __attribute__((address_space(1))) unsigned int*)(gsrc),                        \
      (__attribute__((address_space(3))) unsigned int*)(ldst), 16, 0, 0)

#define BB 32
#define NN 1024
#define FF 512
#define HH 2048
#define M_ROWS (BB * NN)  // 32768

// ---------------------------------------------------------------- weight casts (fused)
__global__ __launch_bounds__(256) void cvt_pair(const float* __restrict__ a, bf16* __restrict__ da,
                                                const float* __restrict__ b, bf16* __restrict__ db,
                                                int n) {
  int i = blockIdx.x * 256 + threadIdx.x;
  if (i < n) {
    da[i] = __float2bfloat16(a[i]);
    db[i] = __float2bfloat16(b[i]);
  }
}

// ---------------------------------------------------------------- cross-lane xor via LDS crossbar
// ds_swizzle BitMode: offset = (xor<<10) | (or<<5) | and(0x1F). Operates within each 32-lane
// group => valid for xor distance d <= 16. Crossbar permutation: no bank conflicts, LDS pipe
// (lgkmcnt) -- offloads the exchange from the VALU pipe (the measured bottleneck).
template <int IMM>
__device__ __forceinline__ unsigned long long swz64(unsigned long long k) {
  int lo = __builtin_amdgcn_ds_swizzle((int)(unsigned)k, IMM);
  int hi = __builtin_amdgcn_ds_swizzle((int)(unsigned)(k >> 32), IMM);
  return (((unsigned long long)(unsigned)hi) << 32) | (unsigned)lo;
}

// ---------------------------------------------------------------- stable argsort per row
// One row of 512 per WAVE; 8 u64 keys/lane in registers.
// key = mono_u32(val) << 32 | orig_idx   (unique keys, idx tie-break => stable argsort)
// Cross-lane levels (j>=8): ds_swizzle xor for d in {1,2,4,8,16}, __shfl_xor (bpermute) for d=32.
// All 16 swizzles of a level issue before the selects (batch -> one lgkm wait window).
// xs semantics (harness-verified in R0/R1): xs[srt[v]] = x[v] -- the ORIGINAL value at this
// thread's position v, NOT the sorted value. Scatter vals[r], never the key payload.
__global__ __launch_bounds__(256) void sort_rows_wave(const float* __restrict__ x,
                                                      unsigned* __restrict__ xs_pack,
                                                      unsigned* __restrict__ srt_pack) {
  __shared__ __align__(16) unsigned short scatx[4 * FF];  // 4 waves/block, 512 u16 per row
  const int t = threadIdx.x;
  const int lane = t & 63;
  const int w = t >> 6;
  const size_t row = (size_t)blockIdx.x * 4 + w;
  const float* xr = x + row * FF;

  float4 v0 = *(const float4*)(xr + lane * 8);
  float4 v1 = *(const float4*)(xr + lane * 8 + 4);
  float vals[8] = {v0.x, v0.y, v0.z, v0.w, v1.x, v1.y, v1.z, v1.w};

  unsigned long long key[8];
#pragma unroll
  for (int r = 0; r < 8; r++) {
    unsigned u = __float_as_uint(vals[r]);
    unsigned s = u ^ ((unsigned)((int)u >> 31) | 0x80000000u);  // monotone fp32->u32
    key[r] = ((unsigned long long)s << 32) | (unsigned)(lane * 8 + r);
  }

#pragma unroll
  for (int k = 2; k <= 512; k <<= 1) {
#pragma unroll
    for (int j = k >> 1; j > 0; j >>= 1) {
      if (j >= 8) {
        const int d = j >> 3;  // lane distance: 1,2,4,8,16,32
        // ---- batch exchange (LDS crossbar / bpermute), then select
        unsigned long long o[8];
#pragma unroll
        for (int r = 0; r < 8; r++) {
          if (d == 1)       o[r] = swz64<0x041F>(key[r]);
          else if (d == 2)  o[r] = swz64<0x081F>(key[r]);
          else if (d == 4)  o[r] = swz64<0x101F>(key[r]);
          else if (d == 8)  o[r] = swz64<0x201F>(key[r]);
          else if (d == 16) o[r] = swz64<0x401F>(key[r]);
          else              o[r] = __shfl_xor(key[r], 32, 64);
        }
        // k >= 16 here, so asc is r-independent: hoist direction out of the r-loop
        bool asc = (((lane * 8) & k) == 0);
        bool lower = ((lane & d) == 0);
        bool keep = (asc == lower);  // keep the min element?
#pragma unroll
        for (int r = 0; r < 8; r++) {
          bool mine = key[r] < o[r];
          key[r] = (mine == keep) ? key[r] : o[r];
        }
      } else {
#pragma unroll
        for (int r = 0; r < 8; r++) {
          if ((r & j) == 0) {
            const int a = r, b = r | j;
            bool asc = (((lane * 8 + a) & k) == 0);
            unsigned long long ka = key[a], kb = key[b];
            bool sw = ((ka > kb) == asc);
            key[a] = sw ? kb : ka;
            key[b] = sw ? ka : kb;
          }
        }
      }
    }
  }

  // xs scatter: sorted position v = lane*8+r holds original index j = srt[v];
  // xs[j] = bf16(x[v]) = bf16(vals[r])  (original value at v -- harness-verified semantics)
  const int base = w * FF;
  unsigned j8[8];
#pragma unroll
  for (int r = 0; r < 8; r++) {
    j8[r] = (unsigned)key[r] & 0xFFFFu;
    __hip_bfloat16 hb = __float2bfloat16(vals[r]);
    scatx[base + j8[r]] = *(unsigned short*)&hb;
  }

  // srt: direct coalesced pack (8 u16 -> uint4)
  uint4 so;
  so.x = j8[0] | (j8[1] << 16);
  so.y = j8[2] | (j8[3] << 16);
  so.z = j8[4] | (j8[5] << 16);
  so.w = j8[6] | (j8[7] << 16);
  *(uint4*)(srt_pack + row * 256 + lane * 4) = so;

  __syncthreads();
  uint4 xo = *(const uint4*)&scatx[base + lane * 8];
  *(uint4*)(xs_pack + row * 256 + lane * 4) = xo;
}

// ---------------------------------------------------------------- 8-phase 256x256 GEMM (T2+T3+T4+T5)
// 512 threads = 8 waves (2 waveM x 4 waveN); per-wave output 128x64; BK=64 split as 2 k-halves of 32.
// LDS 128 KiB: A[2buf][2kh][256][32] at S[0..32768), B same at S[32768..65536), bf16.
// Swizzle (T2): 16B slot-in-row c_phys = c_log ^ ((row>>1)&3). global_load_lds writes linearly,
// so the SOURCE is pre-swizzled (rule #21) and ds_read applies the same XOR.
// Schedule (T3/T4): per K-tile 4 phases (mh,ks); phase = {ds_read frags; issue 1 half-stage (2 loads);
// s_barrier; lgkmcnt(0); setprio(1); 16 MFMA; setprio(0); [vmcnt(4) at P2/P4]; s_barrier}.
// NO __syncthreads anywhere (it would drain vmcnt(0) and kill the pipeline).
template <int RELU, int ADDX, int K, int N>
__global__ __launch_bounds__(512, 2) void gemm8p(const bf16* __restrict__ A,
                                                 const bf16* __restrict__ Bw,
                                                 const float* __restrict__ bias,
                                                 const bf16* __restrict__ xs_add,
                                                 bf16* __restrict__ C) {
  __shared__ __align__(16) bf16 S[65536];  // 128 KiB
  const int t = threadIdx.x;
  const int lane = t & 63, wave = t >> 6;
  const int waveM = wave >> 2, waveN = wave & 3;
  const size_t mBase = (size_t)blockIdx.x * 256;
  const size_t nBase = (size_t)blockIdx.y * 256;

  // staging: thread covers 16B slot s = t (+512 for second load); row = s>>2, pre-swizzled col
  const int srow = t >> 2;                        // 0..127 (second load: +128)
  const int sclog = (t & 3) ^ ((t >> 3) & 3);     // inverse-swizzled source col slot
  const bf16* Asrc0 = A + (mBase + srow) * (size_t)K + sclog * 8;
  const bf16* Bsrc0 = Bw + (nBase + srow) * (size_t)K + sclog * 8;
  const int sdA = wave * 512;                     // LDS dest (elements), + region base
  const int sdB = 32768 + wave * 512;

  // fragment reads: row = (tile-row) + fr, swizzled 16B slot = (lane>>4) ^ ((fr>>1)&3)
  const int fr = lane & 15;
  const int swz8 = ((lane >> 4) ^ ((lane >> 1) & 3)) * 8;
  const int aRd = (waveM * 128 + fr) * 32 + swz8;           // + region + mh*2048 + i*512
  const int bRd = 32768 + (waveN * 64 + fr) * 32 + swz8;    // + region(buf,ks) + nt*512

#define STAGE_A(tt, ks)                                           \
  do {                                                            \
    const int rb_ = (((tt) & 1) * 2 + (ks)) * 8192 + sdA;         \
    const bf16* g_ = Asrc0 + (size_t)(tt) * 64 + (ks) * 32;       \
    ASYNC_CP16(g_, &S[rb_]);                                      \
    ASYNC_CP16(g_ + (size_t)128 * K, &S[rb_ + 4096]);             \
  } while (0)
#define STAGE_B(tt, ks)                                           \
  do {                                                            \
    const int rb_ = (((tt) & 1) * 2 + (ks)) * 8192 + sdB;         \
    const bf16* g_ = Bsrc0 + (size_t)(tt) * 64 + (ks) * 32;       \
    ASYNC_CP16(g_, &S[rb_]);                                      \
    ASYNC_CP16(g_ + (size_t)128 * K, &S[rb_ + 4096]);             \
  } while (0)

  f32x4 acc[8][4];
  f32x4 zero = {0.f, 0.f, 0.f, 0.f};
#pragma unroll
  for (int i = 0; i < 8; i++)
#pragma unroll
    for (int j = 0; j < 4; j++) acc[i][j] = zero;

  // prologue: stage tile 0 fully; k0 halves guaranteed, k1 halves stay in flight
  STAGE_A(0, 0);
  STAGE_B(0, 0);
  STAGE_A(0, 1);
  STAGE_B(0, 1);
  asm volatile("s_waitcnt vmcnt(4)" ::: "memory");
  __builtin_amdgcn_s_barrier();

  const int NT = K / 64;
  for (int kt = 0; kt < NT; ++kt) {
    const int buf = kt & 1;
    const bool pf = (kt + 1 < NT);
    bf16x8 af[4], bq[4];

    // ---- P1: (mh=0, ks=0)
    {
      const int rg = buf * 16384;
#pragma unroll
      for (int i = 0; i < 4; i++) af[i] = *(const bf16x8*)&S[rg + aRd + i * 512];
#pragma unroll
      for (int n = 0; n < 4; n++) bq[n] = *(const bf16x8*)&S[rg + bRd + n * 512];
      if (pf) STAGE_A(kt + 1, 0);
      __builtin_amdgcn_s_barrier();
      asm volatile("s_waitcnt lgkmcnt(0)" ::: "memory");
      __builtin_amdgcn_sched_barrier(0);
      __builtin_amdgcn_s_setprio(1);
#pragma unroll
      for (int i = 0; i < 4; i++)
#pragma unroll
        for (int n = 0; n < 4; n++)
          acc[i][n] = __builtin_amdgcn_mfma_f32_16x16x32_bf16(af[i], bq[n], acc[i][n], 0, 0, 0);
      __builtin_amdgcn_s_setprio(0);
      __builtin_amdgcn_s_barrier();
    }
    // ---- P2: (mh=1, ks=0) — reuse bq
    {
      const int rg = buf * 16384;
#pragma unroll
      for (int i = 0; i < 4; i++) af[i] = *(const bf16x8*)&S[rg + aRd + 2048 + i * 512];
      if (pf) STAGE_B(kt + 1, 0);
      __builtin_amdgcn_s_barrier();
      asm volatile("s_waitcnt lgkmcnt(0)" ::: "memory");
      __builtin_amdgcn_sched_barrier(0);
      __builtin_amdgcn_s_setprio(1);
#pragma unroll
      for (int i = 0; i < 4; i++)
#pragma unroll
        for (int n = 0; n < 4; n++)
          acc[4 + i][n] = __builtin_amdgcn_mfma_f32_16x16x32_bf16(af[i], bq[n], acc[4 + i][n], 0, 0, 0);
      __builtin_amdgcn_s_setprio(0);
      if (pf) asm volatile("s_waitcnt vmcnt(4)" ::: "memory");
      else    asm volatile("s_waitcnt vmcnt(0)" ::: "memory");
      __builtin_amdgcn_s_barrier();
    }
    // ---- P3: (mh=0, ks=1)
    {
      const int rg = buf * 16384 + 8192;
#pragma unroll
      for (int i = 0; i < 4; i++) af[i] = *(const bf16x8*)&S[rg + aRd + i * 512];
#pragma unroll
      for (int n = 0; n < 4; n++) bq[n] = *(const bf16x8*)&S[rg + bRd + n * 512];
      if (pf) STAGE_A(kt + 1, 1);
      __builtin_amdgcn_s_barrier();
      asm volatile("s_waitcnt lgkmcnt(0)" ::: "memory");
      __builtin_amdgcn_sched_barrier(0);
      __builtin_amdgcn_s_setprio(1);
#pragma unroll
      for (int i = 0; i < 4; i++)
#pragma unroll
        for (int n = 0; n < 4; n++)
          acc[i][n] = __builtin_amdgcn_mfma_f32_16x16x32_bf16(af[i], bq[n], acc[i][n], 0, 0, 0);
      __builtin_amdgcn_s_setprio(0);
      __builtin_amdgcn_s_barrier();
    }
    // ---- P4: (mh=1, ks=1)
    {
      const int rg = buf * 16384 + 8192;
#pragma unroll
      for (int i = 0; i < 4; i++) af[i] = *(const bf16x8*)&S[rg + aRd + 2048 + i * 512];
      if (pf) STAGE_B(kt + 1, 1);
      __builtin_amdgcn_s_barrier();
      asm volatile("s_waitcnt lgkmcnt(0)" ::: "memory");
      __builtin_amdgcn_sched_barrier(0);
      __builtin_amdgcn_s_setprio(1);
#pragma unroll
      for (int i = 0; i < 4; i++)
#pragma unroll
        for (int n = 0; n < 4; n++)
          acc[4 + i][n] = __builtin_amdgcn_mfma_f32_16x16x32_bf16(af[i], bq[n], acc[4 + i][n], 0, 0, 0);
      __builtin_amdgcn_s_setprio(0);
      if (pf) asm volatile("s_waitcnt vmcnt(4)" ::: "memory");
      __builtin_amdgcn_s_barrier();
    }
  }
#undef STAGE_A
#undef STAGE_B

  // epilogue: C/D layout col=lane&15, row=(lane>>4)*4+reg (harness-verified mapping)
  const int cn = lane & 15;
  const int cm = (lane >> 4) * 4;
  float b4[4];
#pragma unroll
  for (int n = 0; n < 4; n++) b4[n] = bias[nBase + waveN * 64 + n * 16 + cn];
#pragma unroll
  for (int mt = 0; mt < 8; mt++) {
#pragma unroll
    for (int n = 0; n < 4; n++) {
      size_t gn = nBase + waveN * 64 + n * 16 + cn;
#pragma unroll
      for (int r = 0; r < 4; r++) {
        size_t gm = mBase + waveM * 128 + mt * 16 + cm + r;
        float v = acc[mt][n][r] + b4[n];
        if (RELU) v = fmaxf(v, 0.f);
        if (ADDX) v += __bfloat162float(xs_add[gm * (size_t)N + gn]);
        C[gm * (size_t)N + gn] = __float2bfloat16(v);
      }
    }
  }
}

// ---------------------------------------------------------------- final permute (pure gather)
__global__ __launch_bounds__(256) void permute_gather(const bf16* __restrict__ zp,
                                                      const unsigned* __restrict__ srt_pack,
                                                      float* __restrict__ out) {
  __shared__ __align__(16) unsigned short zr[4][FF];
  const int t = threadIdx.x;
  const int lane = t & 63;
  const int w = t >> 6;
  const size_t row = (size_t)blockIdx.x * 4 + w;

  *(uint4*)&zr[w][lane * 8] = *(const uint4*)(zp + row * FF + lane * 8);
  uint4 sv = *(const uint4*)(srt_pack + row * 256 + lane * 4);
  __syncthreads();

  unsigned idx[8] = {sv.x & 0xFFFFu, sv.x >> 16, sv.y & 0xFFFFu, sv.y >> 16,
                     sv.z & 0xFFFFu, sv.z >> 16, sv.w & 0xFFFFu, sv.w >> 16};
  float4 o0, o1;
#pragma unroll
  for (int r = 0; r < 8; r++) {
    float zf = __uint_as_float(((unsigned)zr[w][idx[r]]) << 16);
    ((r < 4) ? (&o0.x) : (&o1.x))[r & 3] = zf;
  }
  *(float4*)(out + row * FF + lane * 8) = o0;
  *(float4*)(out + row * FF + lane * 8 + 4) = o1;
}

// ---------------------------------------------------------------- launch
extern "C" void kernel_launch(void* const* d_in, const int* in_sizes, int n_in,
                              void* d_out, int out_size, void* d_ws, size_t ws_size,
                              hipStream_t stream) {
  const float* x  = (const float*)d_in[0];
  const float* W1 = (const float*)d_in[1];
  const float* b1 = (const float*)d_in[2];
  const float* W2 = (const float*)d_in[3];
  const float* b2 = (const float*)d_in[4];
  float* out = (float*)d_out;

  char* ws = (char*)d_ws;
  // z aliases xs ([M][512] bf16, identical layout): gemm2 reads xs(gm,gn) then writes
  // z(gm,gn) from the SAME thread, tiles disjoint across blocks -> safe.
  unsigned* xs  = (unsigned*)(ws);                           // 32 MiB bf16 xs
  bf16*     xsb = (bf16*)(ws);
  bf16*     z   = (bf16*)(ws);                               // aliases xs
  unsigned* srt = (unsigned*)(ws + 33554432);                // 32 MiB u16 srt
  bf16* h   = (bf16*)(ws + 67108864);                        // 128 MiB
  bf16* W1b = (bf16*)(ws + 201326592);                       // 2 MiB
  bf16* W2b = (bf16*)(ws + 203423744);                       // 2 MiB

  cvt_pair<<<(HH * FF + 255) / 256, 256, 0, stream>>>(W1, W1b, W2, W2b, HH * FF);
  sort_rows_wave<<<M_ROWS / 4, 256, 0, stream>>>(x, xs, srt);
  // h = relu(xs @ W1^T + b1): M=32768, K=512, N=2048
  gemm8p<1, 0, FF, HH><<<dim3(M_ROWS / 256, HH / 256), 512, 0, stream>>>(xsb, W1b, b1, nullptr, h);
  // z = h @ W2^T + b2 + xs: M=32768, K=2048, N=512  (skip fused, sorted domain)
  gemm8p<0, 1, HH, FF><<<dim3(M_ROWS / 256, FF / 256), 512, 0, stream>>>(h, W2b, b2, xsb, z);
  permute_gather<<<M_ROWS / 4, 256, 0, stream>>>(z, srt, out);
}